// Round 1
// baseline (38.825 us; speedup 1.0000x reference)
//
#include <hip/hip_runtime.h>
#include <math.h>

#define NB   64
#define D    256
#define HW   25
#define HWP  28            // padded row length (float4-friendly, conflict-free: 28 mod 32 covers banks)
#define TRI  32896         // 256*257/2
#define CHUNKS 8
#define CHUNK  (TRI / CHUNKS)   // 4112

// ---------------------------------------------------------------------------
// K1: scaled row means  rm[b][i] = (0.5*exp(T)/256) * sum_j sum_p |f_i+f_j| - |f_i-f_j|
// grid: 64 b * 8 row-tiles of 32 rows.  block: 256 threads = (ii 0..31, g 0..7)
// thread owns row i in registers, sums j in [g*32, g*32+32); f_j is wave-uniform
// LDS broadcast.  Partial sums reduced through LDS.
// ---------------------------------------------------------------------------
__global__ __launch_bounds__(256) void rowsum_kernel(const float* __restrict__ feat,
                                                     const float* __restrict__ temp,
                                                     float* __restrict__ rm) {
    __shared__ __align__(16) float fs[D * HWP];
    __shared__ float psum[32 * 9];      // [ii][g], padded stride 9
    const int tid   = threadIdx.x;
    const int b     = blockIdx.x >> 3;
    const int itile = blockIdx.x & 7;
    const float* fb = feat + (size_t)b * D * HW;

    // stage f[b] into padded LDS
    for (int idx = tid; idx < D * HW; idx += 256) {
        int j = idx / HW;
        int p = idx - j * HW;
        fs[j * HWP + p] = fb[idx];
    }
    // zero the 3 pad floats of each row (tid covers all 256 rows)
    fs[tid * HWP + 25] = 0.f;
    fs[tid * HWP + 26] = 0.f;
    fs[tid * HWP + 27] = 0.f;
    __syncthreads();

    const int ii = tid & 31;
    const int g  = tid >> 5;
    const int i  = itile * 32 + ii;

    float a[HWP];
#pragma unroll
    for (int p = 0; p < HWP; p += 4) {
        float4 v = *reinterpret_cast<const float4*>(&fs[i * HWP + p]);
        a[p] = v.x; a[p + 1] = v.y; a[p + 2] = v.z; a[p + 3] = v.w;
    }

    float acc = 0.f;
    for (int j = g * 32; j < g * 32 + 32; ++j) {
#pragma unroll
        for (int p = 0; p < HWP; p += 4) {
            float4 bv = *reinterpret_cast<const float4*>(&fs[j * HWP + p]);
            acc += fabsf(a[p]     + bv.x) - fabsf(a[p]     - bv.x);
            acc += fabsf(a[p + 1] + bv.y) - fabsf(a[p + 1] - bv.y);
            acc += fabsf(a[p + 2] + bv.z) - fabsf(a[p + 2] - bv.z);
            acc += fabsf(a[p + 3] + bv.w) - fabsf(a[p + 3] - bv.w);
        }
    }
    psum[ii * 9 + g] = acc;
    __syncthreads();

    if (tid < 32) {
        float s = 0.f;
#pragma unroll
        for (int g2 = 0; g2 < 8; ++g2) s += psum[tid * 9 + g2];
        float scale = 0.5f * expf(temp[0]);
        rm[b * D + itile * 32 + tid] = s * scale * (1.0f / 256.0f);
    }
}

// ---------------------------------------------------------------------------
// K2: write triu output with centering:  out[b,k] = scale*e(i,j) - rm[i] - rm[j]
// Flat triangular index k inverted via sqrtf + integer fixup (load-balanced,
// fully coalesced contiguous writes).
// ---------------------------------------------------------------------------
__global__ __launch_bounds__(256) void triu_kernel(const float* __restrict__ feat,
                                                   const float* __restrict__ temp,
                                                   const float* __restrict__ rm,
                                                   float* __restrict__ out) {
    __shared__ __align__(16) float fs[D * HWP];
    __shared__ float rms[D];
    const int tid   = threadIdx.x;
    const int b     = blockIdx.x >> 3;
    const int chunk = blockIdx.x & 7;
    const float* fb = feat + (size_t)b * D * HW;

    for (int idx = tid; idx < D * HW; idx += 256) {
        int j = idx / HW;
        int p = idx - j * HW;
        fs[j * HWP + p] = fb[idx];
    }
    fs[tid * HWP + 25] = 0.f;
    fs[tid * HWP + 26] = 0.f;
    fs[tid * HWP + 27] = 0.f;
    rms[tid] = rm[b * D + tid];
    __syncthreads();

    const float scale = 0.5f * expf(temp[0]);
    float* ob = out + (size_t)b * TRI;
    const int k0 = chunk * CHUNK;
    const int k1 = k0 + CHUNK;   // TRI divisible by CHUNKS

    for (int k = k0 + tid; k < k1; k += 256) {
        // invert row-major triu index: find i with off(i) <= k < off(i+1),
        // off(i) = i*(513-i)/2.   D_disc = (513-2i)^2 at row starts (exact in f32).
        float Df = (float)(263169 - 8 * k);
        float r  = sqrtf(Df);
        int i = (int)((513.0f - r) * 0.5f);
        if (i > 255) i = 255;
        int off = (i * (513 - i)) >> 1;
        if (k < off) {
            --i;
            off = (i * (513 - i)) >> 1;
        } else if (i < 255) {
            int offn = ((i + 1) * (512 - i)) >> 1;
            if (k >= offn) { ++i; off = offn; }
        }
        int j = i + (k - off);

        float acc = 0.f;
#pragma unroll
        for (int p = 0; p < HWP; p += 4) {
            float4 av = *reinterpret_cast<const float4*>(&fs[i * HWP + p]);
            float4 bv = *reinterpret_cast<const float4*>(&fs[j * HWP + p]);
            acc += fabsf(av.x + bv.x) - fabsf(av.x - bv.x);
            acc += fabsf(av.y + bv.y) - fabsf(av.y - bv.y);
            acc += fabsf(av.z + bv.z) - fabsf(av.z - bv.z);
            acc += fabsf(av.w + bv.w) - fabsf(av.w - bv.w);
        }
        ob[k] = acc * scale - rms[i] - rms[j];
    }
}

extern "C" void kernel_launch(void* const* d_in, const int* in_sizes, int n_in,
                              void* d_out, int out_size, void* d_ws, size_t ws_size,
                              hipStream_t stream) {
    const float* feat = (const float*)d_in[0];
    const float* temp = (const float*)d_in[1];
    float* out = (float*)d_out;
    float* rm  = (float*)d_ws;          // 64*256 floats = 64 KB

    rowsum_kernel<<<NB * 8, 256, 0, stream>>>(feat, temp, rm);
    triu_kernel<<<NB * CHUNKS, 256, 0, stream>>>(feat, temp, rm, out);
}

// Round 2
// 31.593 us; speedup vs baseline: 1.2289x; 1.2289x over previous
//
#include <hip/hip_runtime.h>
#include <math.h>

#define NB   64
#define D    256
#define HW   25
#define TRI  32896         // 256*257/2
#define TS   64            // tile size (i and j)
#define PSTR 68            // padded row stride of transposed LDS (floats)

// ---------------------------------------------------------------------------
// K0: zero the rowsum accumulator (64*256 floats in d_ws)
// ---------------------------------------------------------------------------
__global__ void zero_rs(float* __restrict__ rs) {
    rs[blockIdx.x * 256 + threadIdx.x] = 0.f;
}

// ---------------------------------------------------------------------------
// K1: compute raw e(i,j) = sum_p |f_i+f_j| - |f_i-f_j| for one 64x64 tile of
// the triu, write e to d_out (raw), accumulate raw full-row sums into rs via
// symmetry (i-partials + mirrored j-partials; diagonal tiles i-only).
// grid: 64 batches * 10 triu tiles.  block: 256 = 16(tx:j) x 16(ty:i),
// each thread owns a 4x4 output sub-tile.
// LDS layout is TRANSPOSED (as[p][row]) so per p a thread needs exactly two
// float4 reads (4 i-values, 4 j-values) feeding 64 VALU ops.
// ---------------------------------------------------------------------------
__global__ __launch_bounds__(256) void tile_kernel(const float* __restrict__ feat,
                                                   float* __restrict__ out,
                                                   float* __restrict__ rs) {
    __shared__ __align__(16) float as[HW * PSTR];
    __shared__ __align__(16) float bs[HW * PSTR];
    __shared__ float rp[2][TS][17];      // [0]: i-partials by tx; [1]: j-partials by ty

    const int tid = threadIdx.x;
    const int blk = blockIdx.x;
    const int b   = blk / 10;
    const int t   = blk - b * 10;
    const int bi  = (t < 4) ? 0 : (t < 7) ? 1 : (t < 9) ? 2 : 3;
    const int o4  = (bi == 0) ? 0 : (bi == 1) ? 4 : (bi == 2) ? 7 : 9;
    const int bj  = bi + (t - o4);
    const int ibase = bi * TS, jbase = bj * TS;

    const float* fb = feat + (size_t)b * D * HW;

    // stage tile rows, transposed: as[p*PSTR + r] = f[ibase+r][p]
    for (int idx = tid; idx < TS * HW; idx += 256) {
        int r = idx / HW;
        int p = idx - r * HW;
        as[p * PSTR + r] = fb[(ibase + r) * HW + p];
        bs[p * PSTR + r] = fb[(jbase + r) * HW + p];
    }
    __syncthreads();

    const int tx = tid & 15;
    const int ty = tid >> 4;

    float acc[4][4] = {{0.f}};
    for (int p = 0; p < HW; ++p) {
        float4 av = *reinterpret_cast<const float4*>(&as[p * PSTR + ty * 4]);
        float4 bv = *reinterpret_cast<const float4*>(&bs[p * PSTR + tx * 4]);
        float a4[4] = {av.x, av.y, av.z, av.w};
        float b4[4] = {bv.x, bv.y, bv.z, bv.w};
#pragma unroll
        for (int r = 0; r < 4; ++r)
#pragma unroll
            for (int q = 0; q < 4; ++q)
                acc[r][q] += fabsf(a4[r] + b4[q]) - fabsf(a4[r] - b4[q]);
    }

    // write raw e to triu positions in d_out
    float* ob = out + (size_t)b * TRI;
    const bool diag = (bi == bj);
#pragma unroll
    for (int r = 0; r < 4; ++r) {
        const int i = ibase + ty * 4 + r;
        const int rowoff = (i * (513 - i)) >> 1;
#pragma unroll
        for (int q = 0; q < 4; ++q) {
            const int j = jbase + tx * 4 + q;
            if (!diag || j >= i) ob[rowoff + (j - i)] = acc[r][q];
        }
    }

    // rowsum partials
    float pi[4], pj[4];
#pragma unroll
    for (int r = 0; r < 4; ++r) pi[r] = acc[r][0] + acc[r][1] + acc[r][2] + acc[r][3];
#pragma unroll
    for (int q = 0; q < 4; ++q) pj[q] = acc[0][q] + acc[1][q] + acc[2][q] + acc[3][q];
#pragma unroll
    for (int r = 0; r < 4; ++r) rp[0][ty * 4 + r][tx] = pi[r];
#pragma unroll
    for (int q = 0; q < 4; ++q) rp[1][tx * 4 + q][ty] = pj[q];
    __syncthreads();

    if (tid < TS) {
        float si = 0.f;
#pragma unroll
        for (int x = 0; x < 16; ++x) si += rp[0][tid][x];
        atomicAdd(&rs[b * D + ibase + tid], si);
        if (!diag) {
            float sj = 0.f;
#pragma unroll
            for (int x = 0; x < 16; ++x) sj += rp[1][tid][x];
            atomicAdd(&rs[b * D + jbase + tid], sj);
        }
    }
}

// ---------------------------------------------------------------------------
// K2: elementwise centering+scaling in place on d_out:
//   out[b,k] = sc*e - sc/256*(rs[i] + rs[j]),  sc = 0.5*exp(T)
// ---------------------------------------------------------------------------
__global__ __launch_bounds__(256) void center_kernel(const float* __restrict__ temp,
                                                     const float* __restrict__ rs,
                                                     float* __restrict__ out) {
    const float sc  = 0.5f * expf(temp[0]);
    const float scm = sc * (1.0f / 256.0f);
    const int total = NB * TRI;
    for (int idx = blockIdx.x * 256 + threadIdx.x; idx < total; idx += gridDim.x * 256) {
        const int b = idx / TRI;
        const int k = idx - b * TRI;
        // invert row-major triu index (verified): off(i) = i*(513-i)/2
        float Df = (float)(263169 - 8 * k);
        float r  = sqrtf(Df);
        int i = (int)((513.0f - r) * 0.5f);
        if (i > 255) i = 255;
        int off = (i * (513 - i)) >> 1;
        if (k < off) {
            --i;
            off = (i * (513 - i)) >> 1;
        } else if (i < 255) {
            int offn = ((i + 1) * (512 - i)) >> 1;
            if (k >= offn) { ++i; off = offn; }
        }
        const int j = i + (k - off);
        const float e = out[idx];
        out[idx] = sc * e - scm * (rs[b * D + i] + rs[b * D + j]);
    }
}

extern "C" void kernel_launch(void* const* d_in, const int* in_sizes, int n_in,
                              void* d_out, int out_size, void* d_ws, size_t ws_size,
                              hipStream_t stream) {
    const float* feat = (const float*)d_in[0];
    const float* temp = (const float*)d_in[1];
    float* out = (float*)d_out;
    float* rs  = (float*)d_ws;          // 64*256 floats = 64 KB

    zero_rs<<<NB, 256, 0, stream>>>(rs);
    tile_kernel<<<NB * 10, 256, 0, stream>>>(feat, out, rs);
    center_kernel<<<2048, 256, 0, stream>>>(temp, rs, out);
}